// Round 1
// baseline (5785.519 us; speedup 1.0000x reference)
//
#include <hip/hip_runtime.h>
#include <math.h>

#define NU     32
#define HASHF  1024
#define BASISK 128
#define DD     12288
#define BN     16
#define DEPTH  16

// ---------------------------------------------------------------------------
// xfT[k][b] = x[b][k]   (x is (B,C,H,W) contiguous == (B, D))
__global__ __launch_bounds__(256) void k_transpose(const float* __restrict__ x,
                                                   float* __restrict__ xfT) {
    int i = blockIdx.x * 256 + threadIdx.x;   // i in [0, BN*DD)
    int b = i / DD, k = i % DD;
    xfT[(size_t)k * BN + b] = x[i];
}

// ---------------------------------------------------------------------------
// h partials: h_part[c][b][f] = sum_{k in chunk c} xfT[k][b] * P[k][f]
// grid = 2 * KC_H blocks, 256 threads, 2 cols/thread
__global__ __launch_bounds__(256) void k_matP(const float* __restrict__ xfT,
                                              const float* __restrict__ P,
                                              float* __restrict__ h_part,
                                              int kchunk) {
    int nt = blockIdx.x & 1;
    int c  = blockIdx.x >> 1;
    int t  = threadIdx.x;
    int f0 = nt * 512 + t * 2;
    int kbase = c * kchunk;

    __shared__ float lxf[256 * BN];   // 16 KB max
    float2 acc[BN];
#pragma unroll
    for (int b = 0; b < BN; b++) acc[b] = make_float2(0.f, 0.f);

    for (int ks = 0; ks < kchunk; ks += 256) {
        int cnt = min(256, kchunk - ks);
        for (int j = t; j < cnt * BN; j += 256)
            lxf[j] = xfT[(size_t)(kbase + ks) * BN + j];
        __syncthreads();
        const float* wp = P + (size_t)(kbase + ks) * HASHF + f0;
        for (int kl = 0; kl < cnt; kl++) {
            float2 w = *(const float2*)wp;
            wp += HASHF;
            const float4* xv = (const float4*)&lxf[kl * BN];
#pragma unroll
            for (int q = 0; q < 4; q++) {
                float4 a = xv[q];
                acc[4*q+0].x += a.x * w.x; acc[4*q+0].y += a.x * w.y;
                acc[4*q+1].x += a.y * w.x; acc[4*q+1].y += a.y * w.y;
                acc[4*q+2].x += a.z * w.x; acc[4*q+2].y += a.z * w.y;
                acc[4*q+3].x += a.w * w.x; acc[4*q+3].y += a.w * w.y;
            }
        }
        __syncthreads();
    }
#pragma unroll
    for (int b = 0; b < BN; b++)
        *(float2*)&h_part[(size_t)c * (BN * HASHF) + (size_t)b * HASHF + f0] = acc[b];
}

// h[b][f] = sum_c h_part[c][b][f]
__global__ __launch_bounds__(256) void k_reduceH(const float* __restrict__ h_part,
                                                 float* __restrict__ h, int KC) {
    int i = blockIdx.x * 256 + threadIdx.x;   // BN*HASHF
    float s = 0.f;
    for (int c = 0; c < KC; c++) s += h_part[(size_t)c * (BN * HASHF) + i];
    h[i] = s;
}

// ---------------------------------------------------------------------------
// coeff partials: coeff_part[fc][b][u][k] = sum_{f in chunk fc} h[b][f]*basis[u][f][k]
// grid = 32*8 blocks (u, fchunk), 128 threads (k)
__global__ __launch_bounds__(128) void k_coeff(const float* __restrict__ h,
                                               const float* __restrict__ basis,
                                               float* __restrict__ coeff_part) {
    int u  = blockIdx.x & 31;
    int fc = blockIdx.x >> 5;
    int t  = threadIdx.x;      // k index

    __shared__ float lh[128 * BN];   // [f_local][b], 8 KB
    for (int j = t; j < 128 * BN; j += 128) {
        int fl = j >> 4, b = j & 15;
        lh[j] = h[b * HASHF + fc * 128 + fl];
    }
    __syncthreads();

    float acc[BN];
#pragma unroll
    for (int b = 0; b < BN; b++) acc[b] = 0.f;

    const float* bp = basis + (size_t)u * HASHF * BASISK + (size_t)fc * 128 * BASISK + t;
    for (int fl = 0; fl < 128; fl++) {
        float w = bp[(size_t)fl * BASISK];
        const float4* lv = (const float4*)&lh[fl * BN];
#pragma unroll
        for (int q = 0; q < 4; q++) {
            float4 a = lv[q];
            acc[4*q+0] += a.x * w;
            acc[4*q+1] += a.y * w;
            acc[4*q+2] += a.z * w;
            acc[4*q+3] += a.w * w;
        }
    }
#pragma unroll
    for (int b = 0; b < BN; b++)
        coeff_part[((size_t)fc * BN * NU + (size_t)b * NU + u) * BASISK + t] = acc[b];
}

// ---------------------------------------------------------------------------
// combine coeff partials, compute mags[b][u] = ||proj_{b,u}||^2
// grid = 512 blocks (b*32+u), 128 threads
__global__ __launch_bounds__(128) void k_mags(const float* __restrict__ coeff_part,
                                              const float* __restrict__ basis,
                                              float* __restrict__ coeff_full,
                                              float* __restrict__ mags) {
    int b = blockIdx.x >> 5;
    int u = blockIdx.x & 31;
    int t = threadIdx.x;

    __shared__ float lc[BASISK];
    float cv = 0.f;
    for (int fc = 0; fc < 8; fc++)
        cv += coeff_part[((size_t)fc * BN * NU + (size_t)b * NU + u) * BASISK + t];
    lc[t] = cv;
    coeff_full[((size_t)b * NU + u) * BASISK + t] = cv;
    __syncthreads();

    float ssq = 0.f;
    const float* bu = basis + (size_t)u * HASHF * BASISK;
    for (int f = t; f < HASHF; f += 128) {
        const float4* br = (const float4*)&bu[(size_t)f * BASISK];
        const float4* cr = (const float4*)lc;
        float dot = 0.f;
#pragma unroll
        for (int j = 0; j < 32; j++) {
            float4 bv = br[j], c4 = cr[j];
            dot += bv.x * c4.x + bv.y * c4.y + bv.z * c4.z + bv.w * c4.w;
        }
        ssq += dot * dot;
    }
    __shared__ float red[128];
    red[t] = ssq;
    __syncthreads();
    for (int s = 64; s > 0; s >>= 1) {
        if (t < s) red[t] += red[t + s];
        __syncthreads();
    }
    if (t == 0) mags[b * NU + u] = red[0];
}

// ---------------------------------------------------------------------------
// argmax over masked mags, record route, out += h - proj[sel]
// grid = 128 blocks (b*8+fc), 128 threads (f within chunk)
__global__ __launch_bounds__(128) void k_resid(const float* __restrict__ mags,
                                               const float* __restrict__ coeff_full,
                                               const float* __restrict__ basis,
                                               const float* __restrict__ h,
                                               float* __restrict__ out_acc,
                                               int* __restrict__ routes, int s) {
    int b  = blockIdx.x >> 3;
    int fc = blockIdx.x & 7;
    int t  = threadIdx.x;

    __shared__ int sel_s;
    __shared__ float lc[BASISK];
    if (t == 0) {
        unsigned mask = 0xFFFFFFFFu;
        for (int j = 0; j < s; j++) mask &= ~(1u << routes[b * DEPTH + j]);
        float best = -1.f; int bi = 0;
        for (int u = 0; u < NU; u++) {
            if (mask & (1u << u)) {
                float m = mags[b * NU + u];
                if (m > best) { best = m; bi = u; }
            }
        }
        sel_s = bi;
        if (fc == 0) routes[b * DEPTH + s] = bi;
    }
    __syncthreads();
    int u = sel_s;
    lc[t] = coeff_full[((size_t)b * NU + u) * BASISK + t];
    __syncthreads();

    int f = fc * 128 + t;
    const float4* br = (const float4*)&basis[((size_t)u * HASHF + f) * BASISK];
    const float4* cr = (const float4*)lc;
    float dot = 0.f;
#pragma unroll
    for (int j = 0; j < 32; j++) {
        float4 bv = br[j], c4 = cr[j];
        dot += bv.x * c4.x + bv.y * c4.y + bv.z * c4.z + bv.w * c4.w;
    }
    out_acc[b * HASHF + f] += h[b * HASHF + f] - dot;
}

// ---------------------------------------------------------------------------
// y partials: y_part[c][b][n] = sum_{k in chunk} xfT[k][b] * Wt[k][n]
// grid = 24 * KC_Y blocks, 256 threads, 2 cols/thread
__global__ __launch_bounds__(256) void k_matW(const float* __restrict__ xfT,
                                              const float* __restrict__ Wt,
                                              float* __restrict__ y_part,
                                              int kchunk) {
    int nt = blockIdx.x % 24;
    int c  = blockIdx.x / 24;
    int t  = threadIdx.x;
    int n0 = nt * 512 + t * 2;
    int kbase = c * kchunk;

    __shared__ float lxf[256 * BN];   // 16 KB
    float2 acc[BN];
#pragma unroll
    for (int b = 0; b < BN; b++) acc[b] = make_float2(0.f, 0.f);

    for (int ks = 0; ks < kchunk; ks += 256) {
        int cnt = min(256, kchunk - ks);
        for (int j = t; j < cnt * BN; j += 256)
            lxf[j] = xfT[(size_t)(kbase + ks) * BN + j];
        __syncthreads();
        const float* wp = Wt + (size_t)(kbase + ks) * DD + n0;
        for (int kl = 0; kl < cnt; kl++) {
            float2 w = *(const float2*)wp;
            wp += DD;
            const float4* xv = (const float4*)&lxf[kl * BN];
#pragma unroll
            for (int q = 0; q < 4; q++) {
                float4 a = xv[q];
                acc[4*q+0].x += a.x * w.x; acc[4*q+0].y += a.x * w.y;
                acc[4*q+1].x += a.y * w.x; acc[4*q+1].y += a.y * w.y;
                acc[4*q+2].x += a.z * w.x; acc[4*q+2].y += a.z * w.y;
                acc[4*q+3].x += a.w * w.x; acc[4*q+3].y += a.w * w.y;
            }
        }
        __syncthreads();
    }
#pragma unroll
    for (int b = 0; b < BN; b++)
        *(float2*)&y_part[(size_t)c * (BN * DD) + (size_t)b * DD + n0] = acc[b];
}

// reduce y partials + bias + tanh -> xfT_next (transposed write)
__global__ __launch_bounds__(256) void k_ytanh(const float* __restrict__ y_part,
                                               const float* __restrict__ bias,
                                               const int* __restrict__ routes,
                                               float* __restrict__ xfT_next,
                                               int KC, int s) {
    int i = blockIdx.x * 256 + threadIdx.x;   // BN*DD
    int b = i / DD, n = i % DD;
    float sum = 0.f;
    for (int c = 0; c < KC; c++) sum += y_part[(size_t)c * (BN * DD) + i];
    int u = routes[b * DEPTH + s];
    float v = tanhf(sum + bias[(size_t)u * DD + n]);
    xfT_next[(size_t)n * BN + b] = v;
}

// ---------------------------------------------------------------------------
__global__ __launch_bounds__(256) void k_out(const float* __restrict__ out_acc,
                                             const int* __restrict__ routes,
                                             float* __restrict__ o, int n) {
    int i = blockIdx.x * 256 + threadIdx.x;
    if (i >= n) return;
    if (i < BN * HASHF) o[i] = out_acc[i];
    else o[i] = (float)routes[i - BN * HASHF];
}

// ---------------------------------------------------------------------------
extern "C" void kernel_launch(void* const* d_in, const int* in_sizes, int n_in,
                              void* d_out, int out_size, void* d_ws, size_t ws_size,
                              hipStream_t stream) {
    const float* x     = (const float*)d_in[0];
    const float* P     = (const float*)d_in[1];
    const float* basis = (const float*)d_in[2];
    const float* Wt    = (const float*)d_in[3];
    const float* bias  = (const float*)d_in[4];
    float* out = (float*)d_out;

    float* w = (float*)d_ws;
    size_t off = 0;
    auto alloc = [&](size_t nf) { float* p = w + off; off += nf; return p; };

    float* xfT0       = alloc((size_t)DD * BN);
    float* xfT1       = alloc((size_t)DD * BN);
    float* h          = alloc(BN * HASHF);
    float* out_acc    = alloc(BN * HASHF);
    float* coeff_part = alloc((size_t)8 * BN * NU * BASISK);
    float* coeff_full = alloc((size_t)BN * NU * BASISK);
    float* mags       = alloc(BN * NU);
    int*   routes     = (int*)alloc(BN * DEPTH);

    // choose split-K factors to fit workspace
    int KC_Y = 24, KC_H = 192;
    {
        size_t need = (off + (size_t)KC_Y * BN * DD + (size_t)KC_H * BN * HASHF) * 4;
        if (need > ws_size) { KC_Y = 8; KC_H = 64; }
        need = (off + (size_t)KC_Y * BN * DD + (size_t)KC_H * BN * HASHF) * 4;
        if (need > ws_size) { KC_Y = 4; KC_H = 32; }
    }
    float* y_part = alloc((size_t)KC_Y * BN * DD);
    float* h_part = alloc((size_t)KC_H * BN * HASHF);

    hipMemsetAsync(out_acc, 0, BN * HASHF * sizeof(float), stream);

    // h0 = xf @ P
    k_transpose<<<(BN * DD) / 256, 256, 0, stream>>>(x, xfT0);
    k_matP<<<2 * KC_H, 256, 0, stream>>>(xfT0, P, h_part, DD / KC_H);
    k_reduceH<<<(BN * HASHF) / 256, 256, 0, stream>>>(h_part, h, KC_H);

    for (int s = 0; s < DEPTH; s++) {
        float* cur = (s & 1) ? xfT1 : xfT0;
        float* nxt = (s & 1) ? xfT0 : xfT1;

        k_coeff<<<32 * 8, 128, 0, stream>>>(h, basis, coeff_part);
        k_mags<<<BN * NU, 128, 0, stream>>>(coeff_part, basis, coeff_full, mags);
        k_resid<<<BN * 8, 128, 0, stream>>>(mags, coeff_full, basis, h, out_acc, routes, s);

        k_matW<<<24 * KC_Y, 256, 0, stream>>>(cur, Wt, y_part, DD / KC_Y);
        k_ytanh<<<(BN * DD) / 256, 256, 0, stream>>>(y_part, bias, routes, nxt, KC_Y, s);

        k_matP<<<2 * KC_H, 256, 0, stream>>>(nxt, P, h_part, DD / KC_H);
        k_reduceH<<<(BN * HASHF) / 256, 256, 0, stream>>>(h_part, h, KC_H);
    }

    k_out<<<(16640 + 255) / 256, 256, 0, stream>>>(out_acc, routes, out, out_size);
}

// Round 2
// 3990.997 us; speedup vs baseline: 1.4496x; 1.4496x over previous
//
#include <hip/hip_runtime.h>
#include <math.h>

#define NU     32
#define HASHF  1024
#define BASISK 128
#define DD     12288
#define BN     16
#define DEPTH  16

#define KC_Y   32          // split-K chunks for Wt matmul (kchunk = 384)
#define KCH_Y  384
#define KC_H   64          // split-K chunks for P matmul (kchunk = 192)
#define KCH_H  192

// ---------------------------------------------------------------------------
// xfT[k][b] = x[b][k]
__global__ __launch_bounds__(256) void k_transpose(const float* __restrict__ x,
                                                   float* __restrict__ xfT) {
    int i = blockIdx.x * 256 + threadIdx.x;
    int b = i / DD, k = i % DD;
    xfT[(size_t)k * BN + b] = x[i];
}

// ---------------------------------------------------------------------------
// One-time: S[u] = B_u^T B_u  (128x128 per unit)
// grid = 32*8 (u, itile of 16 rows), 128 threads (j)
__global__ __launch_bounds__(128) void k_S(const float* __restrict__ basis,
                                           float* __restrict__ S) {
    int u  = blockIdx.x >> 3;
    int it = blockIdx.x & 7;
    int t  = threadIdx.x;
    int i0 = it * 16;

    __shared__ float lrow[8 * BASISK];   // 8 rows of B_u
    float acc[16];
#pragma unroll
    for (int i = 0; i < 16; i++) acc[i] = 0.f;

    const float* bu = basis + (size_t)u * HASHF * BASISK;
    for (int fb = 0; fb < HASHF / 8; fb++) {
#pragma unroll
        for (int r = 0; r < 8; r++)
            lrow[r * BASISK + t] = bu[(size_t)(fb * 8 + r) * BASISK + t];
        __syncthreads();
#pragma unroll
        for (int r = 0; r < 8; r++) {
            float wj = lrow[r * BASISK + t];
#pragma unroll
            for (int i = 0; i < 16; i++)
                acc[i] += lrow[r * BASISK + i0 + i] * wj;
        }
        __syncthreads();
    }
#pragma unroll
    for (int i = 0; i < 16; i++)
        S[((size_t)u * BASISK + i0 + i) * BASISK + t] = acc[i];
}

// ---------------------------------------------------------------------------
// Fused: blocks [0,128)  -> coeff partials (reduces h_part inline)
//        blocks [128,896) -> Wt matmul partials (the HBM stream)
__global__ __launch_bounds__(256) void k_big(const float* __restrict__ xfT,
                                             const float* __restrict__ Wt,
                                             float* __restrict__ y_part,
                                             const float* __restrict__ h_part,
                                             const float* __restrict__ basis,
                                             float* __restrict__ coeff_part) {
    __shared__ float smem[KCH_Y * BN];   // 24 KB; coeff path uses first 2 KB*4
    int t = threadIdx.x;

    if (blockIdx.x < 128) {
        // ---- coeff: coeff_part[fc][b][u][k] = sum_{f in chunk} h[b][f]*basis[u][f][k]
        int u2 = blockIdx.x >> 3;           // unit pair
        int fc = blockIdx.x & 7;
        int u  = u2 * 2 + (t >> 7);
        int k  = t & 127;

        // reduce h_part -> lh[fl][b]  (h_part layout [c][f][b])
        for (int j = t; j < 128 * BN; j += 256) {
            int fl = j >> 4, b = j & 15;
            float s = 0.f;
            const float* hp = h_part + (size_t)(fc * 128 + fl) * BN + b;
#pragma unroll 4
            for (int c = 0; c < KC_H; c++) s += hp[(size_t)c * (HASHF * BN)];
            smem[fl * BN + b] = s;
        }
        __syncthreads();

        float acc[BN];
#pragma unroll
        for (int b = 0; b < BN; b++) acc[b] = 0.f;
        const float* bp = basis + ((size_t)u * HASHF + fc * 128) * BASISK + k;
        for (int fl = 0; fl < 128; fl++) {
            float w = bp[(size_t)fl * BASISK];
            const float4* lv = (const float4*)&smem[fl * BN];
#pragma unroll
            for (int q = 0; q < 4; q++) {
                float4 a = lv[q];
                acc[4*q+0] += a.x * w;
                acc[4*q+1] += a.y * w;
                acc[4*q+2] += a.z * w;
                acc[4*q+3] += a.w * w;
            }
        }
#pragma unroll
        for (int b = 0; b < BN; b++)
            coeff_part[((size_t)(fc * BN + b) * NU + u) * BASISK + k] = acc[b];
    } else {
        // ---- Wt matmul partials: y_part[c][b][n]
        int m  = blockIdx.x - 128;
        int nt = m % 24;
        int c  = m / 24;
        int n0 = nt * 512 + t * 2;
        int kbase = c * KCH_Y;

        for (int j = t; j < KCH_Y * BN; j += 256)
            smem[j] = xfT[(size_t)kbase * BN + j];
        __syncthreads();

        float2 acc[BN];
#pragma unroll
        for (int b = 0; b < BN; b++) acc[b] = make_float2(0.f, 0.f);

        const float* wp = Wt + (size_t)kbase * DD + n0;
        for (int kl = 0; kl < KCH_Y; kl += 8) {
            float2 w[8];
#pragma unroll
            for (int r = 0; r < 8; r++)
                w[r] = *(const float2*)(wp + (size_t)(kl + r) * DD);
#pragma unroll
            for (int r = 0; r < 8; r++) {
                const float4* xv = (const float4*)&smem[(kl + r) * BN];
#pragma unroll
                for (int q = 0; q < 4; q++) {
                    float4 a = xv[q];
                    acc[4*q+0].x += a.x * w[r].x; acc[4*q+0].y += a.x * w[r].y;
                    acc[4*q+1].x += a.y * w[r].x; acc[4*q+1].y += a.y * w[r].y;
                    acc[4*q+2].x += a.z * w[r].x; acc[4*q+2].y += a.z * w[r].y;
                    acc[4*q+3].x += a.w * w[r].x; acc[4*q+3].y += a.w * w[r].y;
                }
            }
        }
#pragma unroll
        for (int b = 0; b < BN; b++)
            *(float2*)&y_part[(size_t)c * (BN * DD) + (size_t)b * DD + n0] = acc[b];
    }
}

// ---------------------------------------------------------------------------
// mags[b][u] = c^T S_u c ; also materialize coeff_full
// grid = 512 (b*32+u), 128 threads
__global__ __launch_bounds__(128) void k_mags(const float* __restrict__ coeff_part,
                                              const float* __restrict__ S,
                                              float* __restrict__ coeff_full,
                                              float* __restrict__ mags) {
    int b = blockIdx.x >> 5;
    int u = blockIdx.x & 31;
    int t = threadIdx.x;

    __shared__ float lc[BASISK];
    __shared__ float red[BASISK];

    float cv = 0.f;
#pragma unroll
    for (int fc = 0; fc < 8; fc++)
        cv += coeff_part[((size_t)(fc * BN + b) * NU + u) * BASISK + t];
    lc[t] = cv;
    coeff_full[((size_t)b * NU + u) * BASISK + t] = cv;
    __syncthreads();

    // v_t = sum_i S[u][i][t] * c_i   (coalesced over t)
    float v = 0.f;
    const float* Sp = S + (size_t)u * BASISK * BASISK + t;
#pragma unroll 4
    for (int i = 0; i < BASISK; i++) v += Sp[(size_t)i * BASISK] * lc[i];

    red[t] = v * cv;
    __syncthreads();
    for (int s = 64; s > 0; s >>= 1) {
        if (t < s) red[t] += red[t + s];
        __syncthreads();
    }
    if (t == 0) mags[b * NU + u] = red[0];
}

// ---------------------------------------------------------------------------
// argmax (masked by route history), record route, out_acc += h - B_sel c_sel
// grid = 128 (b*8+fc), 128 threads (f in chunk)
__global__ __launch_bounds__(128) void k_resid(const float* __restrict__ mags,
                                               const float* __restrict__ coeff_full,
                                               const float* __restrict__ basis,
                                               const float* __restrict__ h_part,
                                               float* __restrict__ out_acc,
                                               int* __restrict__ routes, int s) {
    int b  = blockIdx.x >> 3;
    int fc = blockIdx.x & 7;
    int t  = threadIdx.x;

    __shared__ int sel_s;
    __shared__ float lc[BASISK];
    if (t == 0) {
        unsigned mask = 0xFFFFFFFFu;
        for (int j = 0; j < s; j++) mask &= ~(1u << routes[b * DEPTH + j]);
        float best = -1.f; int bi = 0;
        for (int u = 0; u < NU; u++) {
            if (mask & (1u << u)) {
                float m = mags[b * NU + u];
                if (m > best) { best = m; bi = u; }
            }
        }
        sel_s = bi;
        if (fc == 0) routes[b * DEPTH + s] = bi;
    }
    __syncthreads();
    int u = sel_s;
    lc[t] = coeff_full[((size_t)b * NU + u) * BASISK + t];
    __syncthreads();

    int f = fc * 128 + t;
    // h[b][f] from h_part ([c][f][b])
    float hv = 0.f;
    const float* hp = h_part + (size_t)f * BN + b;
#pragma unroll 4
    for (int c = 0; c < KC_H; c++) hv += hp[(size_t)c * (HASHF * BN)];

    const float4* br = (const float4*)&basis[((size_t)u * HASHF + f) * BASISK];
    const float4* cr = (const float4*)lc;
    float dot = 0.f;
#pragma unroll
    for (int j = 0; j < 32; j++) {
        float4 bv = br[j], c4 = cr[j];
        dot += bv.x * c4.x + bv.y * c4.y + bv.z * c4.z + bv.w * c4.w;
    }
    out_acc[b * HASHF + f] += hv - dot;
}

// ---------------------------------------------------------------------------
// reduce y partials + bias + tanh -> xfT_next (transposed)
__global__ __launch_bounds__(256) void k_ytanh(const float* __restrict__ y_part,
                                               const float* __restrict__ bias,
                                               const int* __restrict__ routes,
                                               float* __restrict__ xfT_next, int s) {
    int i = blockIdx.x * 256 + threadIdx.x;
    int b = i / DD, n = i % DD;
    float sum = 0.f;
#pragma unroll 4
    for (int c = 0; c < KC_Y; c++) sum += y_part[(size_t)c * (BN * DD) + i];
    int u = routes[b * DEPTH + s];
    float v = tanhf(sum + bias[(size_t)u * DD + n]);
    xfT_next[(size_t)n * BN + b] = v;
}

// ---------------------------------------------------------------------------
// h partials: h_part[c][f][b] = sum_{k in chunk} xfT[k][b] * P[k][f]
// grid = 2 * KC_H (nt, c), 256 threads, 2 cols/thread
__global__ __launch_bounds__(256) void k_matP(const float* __restrict__ xfT,
                                              const float* __restrict__ P,
                                              float* __restrict__ h_part) {
    int nt = blockIdx.x & 1;
    int c  = blockIdx.x >> 1;
    int t  = threadIdx.x;
    int f0 = nt * 512 + t * 2;
    int kbase = c * KCH_H;

    __shared__ float lxf[KCH_H * BN];   // 12 KB
    for (int j = t; j < KCH_H * BN; j += 256)
        lxf[j] = xfT[(size_t)kbase * BN + j];
    __syncthreads();

    float2 acc[BN];
#pragma unroll
    for (int b = 0; b < BN; b++) acc[b] = make_float2(0.f, 0.f);

    const float* wp = P + (size_t)kbase * HASHF + f0;
    for (int kl = 0; kl < KCH_H; kl += 8) {
        float2 w[8];
#pragma unroll
        for (int r = 0; r < 8; r++)
            w[r] = *(const float2*)(wp + (size_t)(kl + r) * HASHF);
#pragma unroll
        for (int r = 0; r < 8; r++) {
            const float4* xv = (const float4*)&lxf[(kl + r) * BN];
#pragma unroll
            for (int q = 0; q < 4; q++) {
                float4 a = xv[q];
                acc[4*q+0].x += a.x * w[r].x; acc[4*q+0].y += a.x * w[r].y;
                acc[4*q+1].x += a.y * w[r].x; acc[4*q+1].y += a.y * w[r].y;
                acc[4*q+2].x += a.z * w[r].x; acc[4*q+2].y += a.z * w[r].y;
                acc[4*q+3].x += a.w * w[r].x; acc[4*q+3].y += a.w * w[r].y;
            }
        }
    }
    // write h_part[c][f][b] (16 consecutive b per f)
    float* hp = h_part + (size_t)c * (HASHF * BN) + (size_t)f0 * BN;
#pragma unroll
    for (int fi = 0; fi < 2; fi++) {
#pragma unroll
        for (int q = 0; q < 4; q++) {
            float4 v;
            v.x = fi ? acc[4*q+0].y : acc[4*q+0].x;
            v.y = fi ? acc[4*q+1].y : acc[4*q+1].x;
            v.z = fi ? acc[4*q+2].y : acc[4*q+2].x;
            v.w = fi ? acc[4*q+3].y : acc[4*q+3].x;
            *(float4*)&hp[fi * BN + q * 4] = v;
        }
    }
}

// ---------------------------------------------------------------------------
__global__ __launch_bounds__(256) void k_out(const float* __restrict__ out_acc,
                                             const int* __restrict__ routes,
                                             float* __restrict__ o, int n) {
    int i = blockIdx.x * 256 + threadIdx.x;
    if (i >= n) return;
    if (i < BN * HASHF) o[i] = out_acc[i];
    else o[i] = (float)routes[i - BN * HASHF];
}

// ---------------------------------------------------------------------------
extern "C" void kernel_launch(void* const* d_in, const int* in_sizes, int n_in,
                              void* d_out, int out_size, void* d_ws, size_t ws_size,
                              hipStream_t stream) {
    const float* x     = (const float*)d_in[0];
    const float* P     = (const float*)d_in[1];
    const float* basis = (const float*)d_in[2];
    const float* Wt    = (const float*)d_in[3];
    const float* bias  = (const float*)d_in[4];
    float* out = (float*)d_out;

    float* w = (float*)d_ws;
    size_t off = 0;
    auto alloc = [&](size_t nf) { float* p = w + off; off += nf; return p; };

    float* xfT0       = alloc((size_t)DD * BN);
    float* xfT1       = alloc((size_t)DD * BN);
    float* out_acc    = alloc(BN * HASHF);
    float* coeff_part = alloc((size_t)8 * BN * NU * BASISK);
    float* coeff_full = alloc((size_t)BN * NU * BASISK);
    float* mags       = alloc(BN * NU);
    float* S          = alloc((size_t)NU * BASISK * BASISK);
    int*   routes     = (int*)alloc(BN * DEPTH);
    float* y_part     = alloc((size_t)KC_Y * BN * DD);
    float* h_part     = alloc((size_t)KC_H * BN * HASHF);
    (void)ws_size;

    hipMemsetAsync(out_acc, 0, BN * HASHF * sizeof(float), stream);

    k_transpose<<<(BN * DD) / 256, 256, 0, stream>>>(x, xfT0);
    k_S<<<NU * 8, 128, 0, stream>>>(basis, S);
    k_matP<<<2 * KC_H, 256, 0, stream>>>(xfT0, P, h_part);

    for (int s = 0; s < DEPTH; s++) {
        float* cur = (s & 1) ? xfT1 : xfT0;
        float* nxt = (s & 1) ? xfT0 : xfT1;

        k_big<<<128 + 24 * KC_Y, 256, 0, stream>>>(cur, Wt, y_part, h_part, basis, coeff_part);
        k_mags<<<BN * NU, 128, 0, stream>>>(coeff_part, S, coeff_full, mags);
        k_resid<<<BN * 8, 128, 0, stream>>>(mags, coeff_full, basis, h_part, out_acc, routes, s);
        k_ytanh<<<(BN * DD) / 256, 256, 0, stream>>>(y_part, bias, routes, nxt, s);
        if (s < DEPTH - 1)
            k_matP<<<2 * KC_H, 256, 0, stream>>>(nxt, P, h_part);
    }

    k_out<<<(BN * HASHF + BN * DEPTH + 255) / 256, 256, 0, stream>>>(out_acc, routes, out, out_size);
}